// Round 14
// baseline (303.102 us; speedup 1.0000x reference)
//
#include <hip/hip_runtime.h>
#include <hip/hip_bf16.h>
#include <math.h>

// Graph transformer attention, round 14:
//  - BALLOT-AGGREGATED two-phase build (replaces 8x dst re-read, ~85us):
//    Phase A (bin): edge list read ONCE; per 64-edge wave batch, per slice:
//    __ballot + popcll -> ONE LDS atomic per wave per slice (R9 did one per
//    EDGE, 8-way conflicted -> serialized); lane writes its (s,d) at
//    base+rank into per-(block,slice) bucket. Phase B (scatter2): block
//    (g,x), blockIdx%8==x -> XCD-affine drain into cursor/csr.
//  - edge_out declared AT FLOOR: 3 structural rewrites all ~125us; FETCH
//    390MB = unique-line combinatorial minimum; 3.2 TB/s = random-64B-line
//    ceiling. Unchanged from R13 (full-head-per-lane).
//  - Keep: qkv MFMA GEMM [Wq|Wv|Wk] perm + LDS-staged epilogue, single-pass
//    softmax, bf16 path, R8 fusion geometry.

#define CAP 64          // fixed slots per node (Poisson(16): P(deg>64)~2e-18)
#define GS 4096         // edges per bin group
#define CAPB 688        // bucket capacity (mean 512 + 8 sigma)

typedef __attribute__((ext_vector_type(8))) short short8;
typedef __attribute__((ext_vector_type(4))) float f32x4;

__device__ inline unsigned short f2bf(float f) {
    unsigned u = __float_as_uint(f);
    unsigned r = u + 0x7fffu + ((u >> 16) & 1u);   // RNE
    return (unsigned short)(r >> 16);
}
__device__ inline float bfhi2f(unsigned u) { return __uint_as_float(u & 0xffff0000u); }
__device__ inline float bflo2f(unsigned u) { return __uint_as_float(u << 16); }

// Permuted fused weight column c' -> source:
//  c' in [0,128): Wq col c' ; [128,256): Wv col c'-128 ; [256,384): Wk col c'-256
__device__ inline float w_perm(const float* Wq, const float* Wk, const float* Wv,
                               int k, int c) {
    if (c < 128)  return Wq[k * 128 + c];
    if (c < 256)  return Wv[k * 128 + (c - 128)];
    return Wk[k * 128 + (c - 256)];
}

// ---------- pack B matrices into MFMA fragment layout (bf16) ----------
__global__ void pack_b_kernel(const float* __restrict__ Wq, const float* __restrict__ Wk,
                              const float* __restrict__ Wv, const float* __restrict__ Wo,
                              const float* __restrict__ bq, const float* __restrict__ bk,
                              const float* __restrict__ bv,
                              short* __restrict__ BqkvP, short* __restrict__ BoP,
                              float* __restrict__ bqkv) {
    int t = blockIdx.x * 256 + threadIdx.x;
    if (t < 24 * 4 * 64 * 8) {
        int j = t & 7, l = (t >> 3) & 63, ks = (t >> 9) & 3, ct = t >> 11;
        int c = ct * 16 + (l & 15);
        int k = ks * 32 + (l >> 4) * 8 + j;
        BqkvP[t] = (short)f2bf(w_perm(Wq, Wk, Wv, k, c));
    }
    if (t < 8 * 4 * 64 * 8) {
        int j = t & 7, l = (t >> 3) & 63, ks = (t >> 9) & 3, ct = t >> 11;
        int c = ct * 16 + (l & 15);
        int k = ks * 32 + (l >> 4) * 8 + j;
        BoP[t] = (short)f2bf(Wo[k * 128 + c]);
    }
    if (t < 384) {   // permuted bias [bq | bv | bk]
        float v;
        if (t < 128)      v = bq[t];
        else if (t < 256) v = bv[t - 128];
        else              v = bk[t - 256];
        bqkv[t] = v;
    }
}

// ---------- MFMA GEMM: [q|v|k] = x @ W' + b', LDS-staged bf16 epilogue ----------
#define QKV_STRIDE 392
__global__ __launch_bounds__(256) void gemm_qkv_mfma(const float* __restrict__ A,
        const short* __restrict__ Bp, const float* __restrict__ bias,
        short* __restrict__ qv, short* __restrict__ kb, int M) {
    __shared__ short stage[4][16][QKV_STRIDE];
    int w = threadIdx.x >> 6, l = threadIdx.x & 63;
    int row0 = blockIdx.x * 64 + w * 16;
    int lr = l & 15, lk = l >> 4;

    f32x4 acc[24];
    #pragma unroll
    for (int ct = 0; ct < 24; ++ct) {
        float b = bias[ct * 16 + lr];
        acc[ct][0] = b; acc[ct][1] = b; acc[ct][2] = b; acc[ct][3] = b;
    }

    int arow = row0 + lr;
    bool rowok = arow < M;
    const float* arp = A + (size_t)arow * 128;

    #pragma unroll
    for (int ks = 0; ks < 4; ++ks) {
        f32x4 a0 = {0.f, 0.f, 0.f, 0.f}, a1 = {0.f, 0.f, 0.f, 0.f};
        if (rowok) {
            a0 = *(const f32x4*)(arp + ks * 32 + lk * 8);
            a1 = *(const f32x4*)(arp + ks * 32 + lk * 8 + 4);
        }
        short8 af;
        af[0] = (short)f2bf(a0[0]); af[1] = (short)f2bf(a0[1]);
        af[2] = (short)f2bf(a0[2]); af[3] = (short)f2bf(a0[3]);
        af[4] = (short)f2bf(a1[0]); af[5] = (short)f2bf(a1[1]);
        af[6] = (short)f2bf(a1[2]); af[7] = (short)f2bf(a1[3]);
        #pragma unroll
        for (int ct = 0; ct < 24; ++ct) {
            short8 bf = *(const short8*)(Bp + ((size_t)(ct * 4 + ks) * 64 + l) * 8);
            acc[ct] = __builtin_amdgcn_mfma_f32_16x16x32_bf16(af, bf, acc[ct], 0, 0, 0);
        }
    }

    #pragma unroll
    for (int ct = 0; ct < 24; ++ct) {
        int c = ct * 16 + lr;
        #pragma unroll
        for (int j = 0; j < 4; ++j)
            stage[w][lk * 4 + j][c] = (short)f2bf(acc[ct][j]);
    }
    __syncthreads();

    #pragma unroll
    for (int it = 0; it < 8; ++it) {
        int rr = it * 2 + (l >> 5);
        int row = row0 + rr;
        if (row < M) {
            short8 vqv = *(const short8*)&stage[w][rr][(l & 31) * 8];
            *(short8*)(qv + (size_t)row * 256 + (l & 31) * 8) = vqv;
        }
    }
    #pragma unroll
    for (int it = 0; it < 4; ++it) {
        int rr = it * 4 + (l >> 4);
        int row = row0 + rr;
        if (row < M) {
            short8 vk = *(const short8*)&stage[w][rr][256 + (l & 15) * 8];
            *(short8*)(kb + (size_t)row * 128 + (l & 15) * 8) = vk;
        }
    }
}

// ---------- Phase A: ballot-aggregated bin by destination XCD slice ----------
// Edge list read ONCE. Per 64-edge wave batch, per slice sl: ballot+popcll ->
// one LDS atomicAdd per wave per slice; lane rank = popcll(mask & below).
__global__ __launch_bounds__(256) void bin_kernel(const int* __restrict__ src,
        const int* __restrict__ dst, uint2* __restrict__ ebuf, int* __restrict__ bcnt,
        int E, unsigned magic) {
    __shared__ int cnt[8];
    int t = threadIdx.x;
    int lane = t & 63;
    if (t < 8) cnt[t] = 0;
    __syncthreads();
    int base = blockIdx.x * GS;
    unsigned long long below = (lane == 63) ? ~0ull >> 1
                                            : ((1ull << lane) - 1);
    #pragma unroll
    for (int i = 0; i < GS / 256; ++i) {
        int e = base + i * 256 + t;
        bool valid = e < E;
        int d = valid ? dst[e] : 0;
        int s = valid ? src[e] : 0;
        unsigned x = (unsigned)(((unsigned long long)(unsigned)d * magic) >> 40);
        #pragma unroll
        for (int sl = 0; sl < 8; ++sl) {
            bool mine = valid && (x == (unsigned)sl);
            unsigned long long m = __ballot(mine);
            int c = __popcll(m);
            int b = 0;
            if (lane == 0 && c > 0) b = atomicAdd(&cnt[sl], c);
            b = __shfl(b, 0);
            if (mine) {
                int pos = b + (int)__popcll(m & below);
                if (pos < CAPB)
                    ebuf[((size_t)blockIdx.x * 8 + sl) * CAPB + pos] =
                        make_uint2((unsigned)s, (unsigned)d);
            }
        }
    }
    __syncthreads();
    if (t < 8) bcnt[blockIdx.x * 8 + t] = cnt[t];
}

// ---------- Phase B: XCD-affine drain into cursor/csr ----------
__global__ __launch_bounds__(256) void scatter2_kernel(const uint2* __restrict__ ebuf,
        const int* __restrict__ bcnt, int* __restrict__ cursor, int* __restrict__ csr) {
    int b = blockIdx.x;
    int c = bcnt[b];
    if (c > CAPB) c = CAPB;
    const uint2* p = ebuf + (size_t)b * CAPB;
    for (int i = threadIdx.x; i < c; i += 256) {
        uint2 sd = p[i];
        int d = (int)sd.y;
        int slot = atomicAdd(&cursor[d], 1);
        if (slot < CAP) csr[((size_t)d << 6) + slot] = (int)sd.x;
    }
}

// ---------- FUSED: edge attention + out-GEMM (full-head-per-lane, R13) ----------
#define AGG_STRIDE 68   // uints per staged row (64 data + 4 pad)

#define EDGE_ITER(EI, ACT)                                                     \
    {                                                                          \
        bool act = (ACT);                                                      \
        int s = act ? (EI) : 0;                                                \
        const uint4* qp = (const uint4*)(qv + (size_t)s * 256 + head * 16);    \
        uint4 qa = qp[0], qb = qp[1];                                          \
        uint4 va = qp[16], vb = qp[17];  /* v row-half: +128 shorts = +16 u4 */\
        float p = bflo2f(qa.x) * kf[0]  + bfhi2f(qa.x) * kf[1]                 \
                + bflo2f(qa.y) * kf[2]  + bfhi2f(qa.y) * kf[3]                 \
                + bflo2f(qa.z) * kf[4]  + bfhi2f(qa.z) * kf[5]                 \
                + bflo2f(qa.w) * kf[6]  + bfhi2f(qa.w) * kf[7]                 \
                + bflo2f(qb.x) * kf[8]  + bfhi2f(qb.x) * kf[9]                 \
                + bflo2f(qb.y) * kf[10] + bfhi2f(qb.y) * kf[11]                \
                + bflo2f(qb.z) * kf[12] + bfhi2f(qb.z) * kf[13]                \
                + bflo2f(qb.w) * kf[14] + bfhi2f(qb.w) * kf[15];               \
        float ee = act ? __expf(p * 0.25f) : 0.f;                              \
        z += ee;                                                               \
        ag[0]  += ee * bflo2f(va.x); ag[1]  += ee * bfhi2f(va.x);              \
        ag[2]  += ee * bflo2f(va.y); ag[3]  += ee * bfhi2f(va.y);              \
        ag[4]  += ee * bflo2f(va.z); ag[5]  += ee * bfhi2f(va.z);              \
        ag[6]  += ee * bflo2f(va.w); ag[7]  += ee * bfhi2f(va.w);              \
        ag[8]  += ee * bflo2f(vb.x); ag[9]  += ee * bfhi2f(vb.x);              \
        ag[10] += ee * bflo2f(vb.y); ag[11] += ee * bfhi2f(vb.y);              \
        ag[12] += ee * bflo2f(vb.z); ag[13] += ee * bfhi2f(vb.z);              \
        ag[14] += ee * bflo2f(vb.w); ag[15] += ee * bfhi2f(vb.w);              \
    }

__global__ __launch_bounds__(256) void edge_out_kernel(const short* __restrict__ qv,
        const short* __restrict__ kb, const int* __restrict__ cursor,
        const int* __restrict__ csr, const short* __restrict__ BoP,
        const float* __restrict__ bo, float* __restrict__ out, int N, int per8) {
    __shared__ unsigned aggLds[16][AGG_STRIDE];
    int w  = threadIdx.x >> 6;
    int l  = threadIdx.x & 63;
    int lr = l & 15, lk = l >> 4;
    int head = l & 7;       // full head (16 dims)
    int slot = l >> 3;      // edge slot 0..7
    int xcd = blockIdx.x & 7;
    int jb  = blockIdx.x >> 3;
    int sliceN = per8 < (N - xcd * per8) ? per8 : (N - xcd * per8);
    int local0 = jb * 16;

    #pragma unroll
    for (int q = 0; q < 4; ++q) {
        int i = w * 4 + q;
        int local = local0 + i;
        if (local < sliceN) {
            int d = xcd * per8 + local;
            int deg = cursor[d];
            int n = (deg < CAP) ? deg : CAP;
            const int* ep = csr + ((size_t)d << 6);

            const uint4* kp = (const uint4*)(kb + (size_t)d * 128 + head * 16);
            uint4 ka = kp[0], kc = kp[1];
            float kf[16];
            kf[0]  = bflo2f(ka.x); kf[1]  = bfhi2f(ka.x);
            kf[2]  = bflo2f(ka.y); kf[3]  = bfhi2f(ka.y);
            kf[4]  = bflo2f(ka.z); kf[5]  = bfhi2f(ka.z);
            kf[6]  = bflo2f(ka.w); kf[7]  = bfhi2f(ka.w);
            kf[8]  = bflo2f(kc.x); kf[9]  = bfhi2f(kc.x);
            kf[10] = bflo2f(kc.y); kf[11] = bfhi2f(kc.y);
            kf[12] = bflo2f(kc.z); kf[13] = bfhi2f(kc.z);
            kf[14] = bflo2f(kc.w); kf[15] = bfhi2f(kc.w);

            float z = 0.f;
            float ag[16];
            #pragma unroll
            for (int j = 0; j < 16; ++j) ag[j] = 0.f;

            for (int b0 = 0; b0 < n; b0 += 16) {
                int i0 = b0 + slot;          // <= 55: bin-safe
                int i1 = b0 + 8 + slot;      // <= 63: bin-safe
                int eA = ep[i0];
                int eB = ep[i1];
                EDGE_ITER(eA, i0 < n)
                EDGE_ITER(eB, i1 < n)
            }

            // slot-reduce (once per node): slots live in lane bits 3-5
            z += __shfl_xor(z, 8);
            z += __shfl_xor(z, 16);
            z += __shfl_xor(z, 32);
            #pragma unroll
            for (int j = 0; j < 16; ++j) {
                ag[j] += __shfl_xor(ag[j], 8);
                ag[j] += __shfl_xor(ag[j], 16);
                ag[j] += __shfl_xor(ag[j], 32);
            }

            float zi = (z > 0.f) ? 1.0f / z : 0.f;
            if (slot == 0) {   // lane 'head' writes dim-pairs [8*head, 8*head+8)
                #pragma unroll
                for (int j = 0; j < 8; ++j) {
                    unsigned pk = (unsigned)f2bf(ag[2 * j] * zi) |
                                  ((unsigned)f2bf(ag[2 * j + 1] * zi) << 16);
                    aggLds[i][head * 8 + j] = pk;
                }
            }
        }
    }
    __syncthreads();

    // cooperative 16-row out-GEMM; wave w -> col tiles 2w, 2w+1
    f32x4 acc[2];
    #pragma unroll
    for (int t = 0; t < 2; ++t) {
        float b = bo[(w * 2 + t) * 16 + lr];
        acc[t][0] = b; acc[t][1] = b; acc[t][2] = b; acc[t][3] = b;
    }

    #pragma unroll
    for (int ks = 0; ks < 4; ++ks) {
        short8 af = *(const short8*)&aggLds[lr][ks * 16 + lk * 4];
        #pragma unroll
        for (int t = 0; t < 2; ++t) {
            int ct = w * 2 + t;
            short8 bf = *(const short8*)(BoP + ((size_t)(ct * 4 + ks) * 64 + l) * 8);
            acc[t] = __builtin_amdgcn_mfma_f32_16x16x32_bf16(af, bf, acc[t], 0, 0, 0);
        }
    }

    #pragma unroll
    for (int t = 0; t < 2; ++t) {
        int c = (w * 2 + t) * 16 + lr;
        #pragma unroll
        for (int j = 0; j < 4; ++j) {
            int localr = local0 + lk * 4 + j;
            if (localr < sliceN) {
                int r = xcd * per8 + localr;
                out[(size_t)r * 128 + c] = acc[t][j];
            }
        }
    }
}

extern "C" void kernel_launch(void* const* d_in, const int* in_sizes, int n_in,
                              void* d_out, int out_size, void* d_ws, size_t ws_size,
                              hipStream_t stream) {
    const float* x   = (const float*)d_in[0];
    const int*   src = (const int*)d_in[1];
    const int*   dst = (const int*)d_in[2];
    const float* Wq  = (const float*)d_in[3];
    const float* bq  = (const float*)d_in[4];
    const float* Wk  = (const float*)d_in[5];
    const float* bk  = (const float*)d_in[6];
    const float* Wv  = (const float*)d_in[7];
    const float* bv  = (const float*)d_in[8];
    const float* Wo  = (const float*)d_in[9];
    const float* bo  = (const float*)d_in[10];
    float* out = (float*)d_out;

    int N = in_sizes[0] / 128;
    int E = in_sizes[1];
    int per8 = (N + 7) / 8;
    unsigned magic = (unsigned)(((1ull << 40) + (unsigned long long)per8 - 1) /
                                (unsigned long long)per8);
    int ngroups = (E + GS - 1) / GS;

    char* ws = (char*)d_ws;
    size_t off = 0;
    auto alloc = [&](size_t bytes) -> void* {
        void* p = ws + off;
        off = (off + bytes + 255) & ~(size_t)255;
        return p;
    };
    short* BqkvP  = (short*)alloc((size_t)24 * 4 * 64 * 8 * 2);
    short* BoP    = (short*)alloc((size_t)8 * 4 * 64 * 8 * 2);
    float* bqkv   = (float*)alloc(384 * 4);
    short* qv     = (short*)alloc((size_t)N * 256 * 2);    // [q128|v128] bf16
    short* kb     = (short*)alloc((size_t)N * 128 * 2);    // k bf16
    int* csr      = (int*)alloc((size_t)N * CAP * 4);      // fixed-capacity bins
    int* cursor   = (int*)alloc((size_t)N * 4);            // dense (slice-local lines)
    uint2* ebuf   = (uint2*)alloc((size_t)ngroups * 8 * CAPB * 8);
    int* bcnt     = (int*)alloc((size_t)ngroups * 8 * 4);
    (void)ws_size; (void)n_in; (void)out_size;

    hipMemsetAsync(cursor, 0, (size_t)N * 4, stream);

    pack_b_kernel<<<192, 256, 0, stream>>>(Wq, Wk, Wv, Wo, bq, bk, bv, BqkvP, BoP, bqkv);

    bin_kernel<<<ngroups, 256, 0, stream>>>(src, dst, ebuf, bcnt, E, magic);

    gemm_qkv_mfma<<<(N + 63) / 64, 256, 0, stream>>>(x, BqkvP, bqkv, qv, kb, N);

    scatter2_kernel<<<ngroups * 8, 256, 0, stream>>>(ebuf, bcnt, cursor, csr);

    int nb16 = (per8 + 15) / 16;
    edge_out_kernel<<<nb16 * 8, 256, 0, stream>>>(qv, kb, cursor, csr, BoP, bo, out, N, per8);
}

// Round 15
// 285.593 us; speedup vs baseline: 1.0613x; 1.0613x over previous
//
#include <hip/hip_runtime.h>
#include <hip/hip_bf16.h>
#include <math.h>

// Graph transformer attention, round 15:
//  - ATOMIC-FREE, SHFL-FREE two-phase build. Phase A (bin): each WAVE owns a
//    private 1024-edge range and private per-slice buckets; slice counters
//    are wave-uniform VGPRs updated with popcll(ballot) -> zero LDS atomics,
//    zero shfl broadcasts (R14's two serialization points). int4 edge loads.
//    Phase B (scatter2): block (chunk,slice), blockIdx%8==slice -> XCD-affine
//    drain of 4 wave-buckets into cursor/csr (R5-proven write pattern).
//    Traffic: ~180MB total vs R13's ~490MB (8x dst re-read, 5.2 TB/s bound).
//  - edge_out at floor (3 rewrites all ~125us; FETCH=unique-line minimum).
//  - Keep: full-head-per-lane edge phase, qkv MFMA GEMM [Wq|Wv|Wk] perm,
//    LDS-staged epilogue, single-pass softmax, bf16 path, R8 fusion geometry.

#define CAP 64          // fixed slots per node (Poisson(16): P(deg>64)~2e-18)
#define GS 4096         // edges per bin block (4 waves x 1024)
#define WEDGE 1024      // edges per wave
#define CAPB 224        // per-(wave,slice) bucket capacity (mean 128 + 9 sigma)

typedef __attribute__((ext_vector_type(8))) short short8;
typedef __attribute__((ext_vector_type(4))) float f32x4;

__device__ inline unsigned short f2bf(float f) {
    unsigned u = __float_as_uint(f);
    unsigned r = u + 0x7fffu + ((u >> 16) & 1u);   // RNE
    return (unsigned short)(r >> 16);
}
__device__ inline float bfhi2f(unsigned u) { return __uint_as_float(u & 0xffff0000u); }
__device__ inline float bflo2f(unsigned u) { return __uint_as_float(u << 16); }

// Permuted fused weight column c' -> source:
//  c' in [0,128): Wq col c' ; [128,256): Wv col c'-128 ; [256,384): Wk col c'-256
__device__ inline float w_perm(const float* Wq, const float* Wk, const float* Wv,
                               int k, int c) {
    if (c < 128)  return Wq[k * 128 + c];
    if (c < 256)  return Wv[k * 128 + (c - 128)];
    return Wk[k * 128 + (c - 256)];
}

// ---------- pack B matrices into MFMA fragment layout (bf16) ----------
__global__ void pack_b_kernel(const float* __restrict__ Wq, const float* __restrict__ Wk,
                              const float* __restrict__ Wv, const float* __restrict__ Wo,
                              const float* __restrict__ bq, const float* __restrict__ bk,
                              const float* __restrict__ bv,
                              short* __restrict__ BqkvP, short* __restrict__ BoP,
                              float* __restrict__ bqkv) {
    int t = blockIdx.x * 256 + threadIdx.x;
    if (t < 24 * 4 * 64 * 8) {
        int j = t & 7, l = (t >> 3) & 63, ks = (t >> 9) & 3, ct = t >> 11;
        int c = ct * 16 + (l & 15);
        int k = ks * 32 + (l >> 4) * 8 + j;
        BqkvP[t] = (short)f2bf(w_perm(Wq, Wk, Wv, k, c));
    }
    if (t < 8 * 4 * 64 * 8) {
        int j = t & 7, l = (t >> 3) & 63, ks = (t >> 9) & 3, ct = t >> 11;
        int c = ct * 16 + (l & 15);
        int k = ks * 32 + (l >> 4) * 8 + j;
        BoP[t] = (short)f2bf(Wo[k * 128 + c]);
    }
    if (t < 384) {   // permuted bias [bq | bv | bk]
        float v;
        if (t < 128)      v = bq[t];
        else if (t < 256) v = bv[t - 128];
        else              v = bk[t - 256];
        bqkv[t] = v;
    }
}

// ---------- MFMA GEMM: [q|v|k] = x @ W' + b', LDS-staged bf16 epilogue ----------
#define QKV_STRIDE 392
__global__ __launch_bounds__(256) void gemm_qkv_mfma(const float* __restrict__ A,
        const short* __restrict__ Bp, const float* __restrict__ bias,
        short* __restrict__ qv, short* __restrict__ kb, int M) {
    __shared__ short stage[4][16][QKV_STRIDE];
    int w = threadIdx.x >> 6, l = threadIdx.x & 63;
    int row0 = blockIdx.x * 64 + w * 16;
    int lr = l & 15, lk = l >> 4;

    f32x4 acc[24];
    #pragma unroll
    for (int ct = 0; ct < 24; ++ct) {
        float b = bias[ct * 16 + lr];
        acc[ct][0] = b; acc[ct][1] = b; acc[ct][2] = b; acc[ct][3] = b;
    }

    int arow = row0 + lr;
    bool rowok = arow < M;
    const float* arp = A + (size_t)arow * 128;

    #pragma unroll
    for (int ks = 0; ks < 4; ++ks) {
        f32x4 a0 = {0.f, 0.f, 0.f, 0.f}, a1 = {0.f, 0.f, 0.f, 0.f};
        if (rowok) {
            a0 = *(const f32x4*)(arp + ks * 32 + lk * 8);
            a1 = *(const f32x4*)(arp + ks * 32 + lk * 8 + 4);
        }
        short8 af;
        af[0] = (short)f2bf(a0[0]); af[1] = (short)f2bf(a0[1]);
        af[2] = (short)f2bf(a0[2]); af[3] = (short)f2bf(a0[3]);
        af[4] = (short)f2bf(a1[0]); af[5] = (short)f2bf(a1[1]);
        af[6] = (short)f2bf(a1[2]); af[7] = (short)f2bf(a1[3]);
        #pragma unroll
        for (int ct = 0; ct < 24; ++ct) {
            short8 bf = *(const short8*)(Bp + ((size_t)(ct * 4 + ks) * 64 + l) * 8);
            acc[ct] = __builtin_amdgcn_mfma_f32_16x16x32_bf16(af, bf, acc[ct], 0, 0, 0);
        }
    }

    #pragma unroll
    for (int ct = 0; ct < 24; ++ct) {
        int c = ct * 16 + lr;
        #pragma unroll
        for (int j = 0; j < 4; ++j)
            stage[w][lk * 4 + j][c] = (short)f2bf(acc[ct][j]);
    }
    __syncthreads();

    #pragma unroll
    for (int it = 0; it < 8; ++it) {
        int rr = it * 2 + (l >> 5);
        int row = row0 + rr;
        if (row < M) {
            short8 vqv = *(const short8*)&stage[w][rr][(l & 31) * 8];
            *(short8*)(qv + (size_t)row * 256 + (l & 31) * 8) = vqv;
        }
    }
    #pragma unroll
    for (int it = 0; it < 4; ++it) {
        int rr = it * 4 + (l >> 4);
        int row = row0 + rr;
        if (row < M) {
            short8 vk = *(const short8*)&stage[w][rr][256 + (l & 15) * 8];
            *(short8*)(kb + (size_t)row * 128 + (l & 15) * 8) = vk;
        }
    }
}

// ---------- Phase A: wave-private atomic-free bin by dst XCD slice ----------
// Wave owns edges [blk*4096 + wv*1024, +1024). Per 256-edge step each lane
// holds 4 edges (int4); per edge-pos, 8 ballots rank lanes into the wave's
// private (wave,slice) bucket; counters are wave-uniform VGPRs (no atomics,
// no shfl). x = d/per8 via magic mul.
__global__ __launch_bounds__(256) void bin_kernel(const int* __restrict__ src,
        const int* __restrict__ dst, uint2* __restrict__ ebuf, int* __restrict__ bcnt,
        int E, unsigned magic) {
    int wv = threadIdx.x >> 6, lane = threadIdx.x & 63;
    int wbase = blockIdx.x * GS + wv * WEDGE;
    unsigned long long below = (lane == 63) ? (~0ull >> 1) : ((1ull << lane) - 1);
    size_t bufbase = ((size_t)blockIdx.x * 4 + wv) * 8;   // bucket-id base

    int wcnt[8];
    #pragma unroll
    for (int sl = 0; sl < 8; ++sl) wcnt[sl] = 0;

    #pragma unroll
    for (int it = 0; it < WEDGE / 256; ++it) {   // 4 iters x 4 edges/lane
        int e0 = wbase + it * 256 + lane * 4;
        int4 d4, s4;
        if (e0 + 3 < E) {
            d4 = *(const int4*)(dst + e0);
            s4 = *(const int4*)(src + e0);
        } else {
            d4 = make_int4(-1, -1, -1, -1);
            s4 = make_int4(0, 0, 0, 0);
            if (e0 < E)     { d4.x = dst[e0];     s4.x = src[e0]; }
            if (e0 + 1 < E) { d4.y = dst[e0 + 1]; s4.y = src[e0 + 1]; }
            if (e0 + 2 < E) { d4.z = dst[e0 + 2]; s4.z = src[e0 + 2]; }
        }
        #pragma unroll
        for (int j = 0; j < 4; ++j) {
            int d = (j == 0) ? d4.x : (j == 1) ? d4.y : (j == 2) ? d4.z : d4.w;
            int s = (j == 0) ? s4.x : (j == 1) ? s4.y : (j == 2) ? s4.z : s4.w;
            unsigned x = (d >= 0)
                ? (unsigned)(((unsigned long long)(unsigned)d * magic) >> 40) : 8u;
            #pragma unroll
            for (int sl = 0; sl < 8; ++sl) {
                unsigned long long m = __ballot(x == (unsigned)sl);
                if (x == (unsigned)sl) {
                    int pos = wcnt[sl] + (int)__popcll(m & below);
                    if (pos < CAPB)
                        ebuf[(bufbase + sl) * CAPB + pos] =
                            make_uint2((unsigned)s, (unsigned)d);
                }
                wcnt[sl] += (int)__popcll(m);   // wave-uniform update
            }
        }
    }
    if (lane == 0) {
        #pragma unroll
        for (int sl = 0; sl < 8; ++sl)
            bcnt[bufbase + sl] = (wcnt[sl] < CAPB) ? wcnt[sl] : CAPB;
    }
}

// ---------- Phase B: XCD-affine drain into cursor/csr ----------
// Block (chunk cb, slice sl=blockIdx%8) drains the 4 wave-buckets of its
// chunk for its slice; all dsts lie in slice sl -> cursor/csr L2-local.
__global__ __launch_bounds__(256) void scatter2_kernel(const uint2* __restrict__ ebuf,
        const int* __restrict__ bcnt, int* __restrict__ cursor, int* __restrict__ csr) {
    int sl = blockIdx.x & 7;
    int cb = blockIdx.x >> 3;
    #pragma unroll
    for (int wv = 0; wv < 4; ++wv) {
        size_t bid = ((size_t)cb * 4 + wv) * 8 + sl;
        int c = bcnt[bid];
        const uint2* p = ebuf + bid * CAPB;
        for (int i = threadIdx.x; i < c; i += 256) {
            uint2 sd = p[i];
            int d = (int)sd.y;
            int slot = atomicAdd(&cursor[d], 1);
            if (slot < CAP) csr[((size_t)d << 6) + slot] = (int)sd.x;
        }
    }
}

// ---------- FUSED: edge attention + out-GEMM (full-head-per-lane, R13) ----------
#define AGG_STRIDE 68   // uints per staged row (64 data + 4 pad)

#define EDGE_ITER(EI, ACT)                                                     \
    {                                                                          \
        bool act = (ACT);                                                      \
        int s = act ? (EI) : 0;                                                \
        const uint4* qp = (const uint4*)(qv + (size_t)s * 256 + head * 16);    \
        uint4 qa = qp[0], qb = qp[1];                                          \
        uint4 va = qp[16], vb = qp[17];  /* v row-half: +128 shorts = +16 u4 */\
        float p = bflo2f(qa.x) * kf[0]  + bfhi2f(qa.x) * kf[1]                 \
                + bflo2f(qa.y) * kf[2]  + bfhi2f(qa.y) * kf[3]                 \
                + bflo2f(qa.z) * kf[4]  + bfhi2f(qa.z) * kf[5]                 \
                + bflo2f(qa.w) * kf[6]  + bfhi2f(qa.w) * kf[7]                 \
                + bflo2f(qb.x) * kf[8]  + bfhi2f(qb.x) * kf[9]                 \
                + bflo2f(qb.y) * kf[10] + bfhi2f(qb.y) * kf[11]                \
                + bflo2f(qb.z) * kf[12] + bfhi2f(qb.z) * kf[13]                \
                + bflo2f(qb.w) * kf[14] + bfhi2f(qb.w) * kf[15];               \
        float ee = act ? __expf(p * 0.25f) : 0.f;                              \
        z += ee;                                                               \
        ag[0]  += ee * bflo2f(va.x); ag[1]  += ee * bfhi2f(va.x);              \
        ag[2]  += ee * bflo2f(va.y); ag[3]  += ee * bfhi2f(va.y);              \
        ag[4]  += ee * bflo2f(va.z); ag[5]  += ee * bfhi2f(va.z);              \
        ag[6]  += ee * bflo2f(va.w); ag[7]  += ee * bfhi2f(va.w);              \
        ag[8]  += ee * bflo2f(vb.x); ag[9]  += ee * bfhi2f(vb.x);              \
        ag[10] += ee * bflo2f(vb.y); ag[11] += ee * bfhi2f(vb.y);              \
        ag[12] += ee * bflo2f(vb.z); ag[13] += ee * bfhi2f(vb.z);              \
        ag[14] += ee * bflo2f(vb.w); ag[15] += ee * bfhi2f(vb.w);              \
    }

__global__ __launch_bounds__(256) void edge_out_kernel(const short* __restrict__ qv,
        const short* __restrict__ kb, const int* __restrict__ cursor,
        const int* __restrict__ csr, const short* __restrict__ BoP,
        const float* __restrict__ bo, float* __restrict__ out, int N, int per8) {
    __shared__ unsigned aggLds[16][AGG_STRIDE];
    int w  = threadIdx.x >> 6;
    int l  = threadIdx.x & 63;
    int lr = l & 15, lk = l >> 4;
    int head = l & 7;       // full head (16 dims)
    int slot = l >> 3;      // edge slot 0..7
    int xcd = blockIdx.x & 7;
    int jb  = blockIdx.x >> 3;
    int sliceN = per8 < (N - xcd * per8) ? per8 : (N - xcd * per8);
    int local0 = jb * 16;

    #pragma unroll
    for (int q = 0; q < 4; ++q) {
        int i = w * 4 + q;
        int local = local0 + i;
        if (local < sliceN) {
            int d = xcd * per8 + local;
            int deg = cursor[d];
            int n = (deg < CAP) ? deg : CAP;
            const int* ep = csr + ((size_t)d << 6);

            const uint4* kp = (const uint4*)(kb + (size_t)d * 128 + head * 16);
            uint4 ka = kp[0], kc = kp[1];
            float kf[16];
            kf[0]  = bflo2f(ka.x); kf[1]  = bfhi2f(ka.x);
            kf[2]  = bflo2f(ka.y); kf[3]  = bfhi2f(ka.y);
            kf[4]  = bflo2f(ka.z); kf[5]  = bfhi2f(ka.z);
            kf[6]  = bflo2f(ka.w); kf[7]  = bfhi2f(ka.w);
            kf[8]  = bflo2f(kc.x); kf[9]  = bfhi2f(kc.x);
            kf[10] = bflo2f(kc.y); kf[11] = bfhi2f(kc.y);
            kf[12] = bflo2f(kc.z); kf[13] = bfhi2f(kc.z);
            kf[14] = bflo2f(kc.w); kf[15] = bfhi2f(kc.w);

            float z = 0.f;
            float ag[16];
            #pragma unroll
            for (int j = 0; j < 16; ++j) ag[j] = 0.f;

            for (int b0 = 0; b0 < n; b0 += 16) {
                int i0 = b0 + slot;          // <= 55: bin-safe
                int i1 = b0 + 8 + slot;      // <= 63: bin-safe
                int eA = ep[i0];
                int eB = ep[i1];
                EDGE_ITER(eA, i0 < n)
                EDGE_ITER(eB, i1 < n)
            }

            // slot-reduce (once per node): slots live in lane bits 3-5
            z += __shfl_xor(z, 8);
            z += __shfl_xor(z, 16);
            z += __shfl_xor(z, 32);
            #pragma unroll
            for (int j = 0; j < 16; ++j) {
                ag[j] += __shfl_xor(ag[j], 8);
                ag[j] += __shfl_xor(ag[j], 16);
                ag[j] += __shfl_xor(ag[j], 32);
            }

            float zi = (z > 0.f) ? 1.0f / z : 0.f;
            if (slot == 0) {   // lane 'head' writes dim-pairs [8*head, 8*head+8)
                #pragma unroll
                for (int j = 0; j < 8; ++j) {
                    unsigned pk = (unsigned)f2bf(ag[2 * j] * zi) |
                                  ((unsigned)f2bf(ag[2 * j + 1] * zi) << 16);
                    aggLds[i][head * 8 + j] = pk;
                }
            }
        }
    }
    __syncthreads();

    // cooperative 16-row out-GEMM; wave w -> col tiles 2w, 2w+1
    f32x4 acc[2];
    #pragma unroll
    for (int t = 0; t < 2; ++t) {
        float b = bo[(w * 2 + t) * 16 + lr];
        acc[t][0] = b; acc[t][1] = b; acc[t][2] = b; acc[t][3] = b;
    }

    #pragma unroll
    for (int ks = 0; ks < 4; ++ks) {
        short8 af = *(const short8*)&aggLds[lr][ks * 16 + lk * 4];
        #pragma unroll
        for (int t = 0; t < 2; ++t) {
            int ct = w * 2 + t;
            short8 bf = *(const short8*)(BoP + ((size_t)(ct * 4 + ks) * 64 + l) * 8);
            acc[t] = __builtin_amdgcn_mfma_f32_16x16x32_bf16(af, bf, acc[t], 0, 0, 0);
        }
    }

    #pragma unroll
    for (int t = 0; t < 2; ++t) {
        int c = (w * 2 + t) * 16 + lr;
        #pragma unroll
        for (int j = 0; j < 4; ++j) {
            int localr = local0 + lk * 4 + j;
            if (localr < sliceN) {
                int r = xcd * per8 + localr;
                out[(size_t)r * 128 + c] = acc[t][j];
            }
        }
    }
}

extern "C" void kernel_launch(void* const* d_in, const int* in_sizes, int n_in,
                              void* d_out, int out_size, void* d_ws, size_t ws_size,
                              hipStream_t stream) {
    const float* x   = (const float*)d_in[0];
    const int*   src = (const int*)d_in[1];
    const int*   dst = (const int*)d_in[2];
    const float* Wq  = (const float*)d_in[3];
    const float* bq  = (const float*)d_in[4];
    const float* Wk  = (const float*)d_in[5];
    const float* bk  = (const float*)d_in[6];
    const float* Wv  = (const float*)d_in[7];
    const float* bv  = (const float*)d_in[8];
    const float* Wo  = (const float*)d_in[9];
    const float* bo  = (const float*)d_in[10];
    float* out = (float*)d_out;

    int N = in_sizes[0] / 128;
    int E = in_sizes[1];
    int per8 = (N + 7) / 8;
    unsigned magic = (unsigned)(((1ull << 40) + (unsigned long long)per8 - 1) /
                                (unsigned long long)per8);
    int nchunks = (E + GS - 1) / GS;

    char* ws = (char*)d_ws;
    size_t off = 0;
    auto alloc = [&](size_t bytes) -> void* {
        void* p = ws + off;
        off = (off + bytes + 255) & ~(size_t)255;
        return p;
    };
    short* BqkvP  = (short*)alloc((size_t)24 * 4 * 64 * 8 * 2);
    short* BoP    = (short*)alloc((size_t)8 * 4 * 64 * 8 * 2);
    float* bqkv   = (float*)alloc(384 * 4);
    short* qv     = (short*)alloc((size_t)N * 256 * 2);    // [q128|v128] bf16
    short* kb     = (short*)alloc((size_t)N * 128 * 2);    // k bf16
    int* csr      = (int*)alloc((size_t)N * CAP * 4);      // fixed-capacity bins
    int* cursor   = (int*)alloc((size_t)N * 4);            // dense (slice-local lines)
    uint2* ebuf   = (uint2*)alloc((size_t)nchunks * 4 * 8 * CAPB * 8);
    int* bcnt     = (int*)alloc((size_t)nchunks * 4 * 8 * 4);
    (void)ws_size; (void)n_in; (void)out_size;

    hipMemsetAsync(cursor, 0, (size_t)N * 4, stream);

    pack_b_kernel<<<192, 256, 0, stream>>>(Wq, Wk, Wv, Wo, bq, bk, bv, BqkvP, BoP, bqkv);

    bin_kernel<<<nchunks, 256, 0, stream>>>(src, dst, ebuf, bcnt, E, magic);

    gemm_qkv_mfma<<<(N + 63) / 64, 256, 0, stream>>>(x, BqkvP, bqkv, qv, kb, N);

    scatter2_kernel<<<nchunks * 8, 256, 0, stream>>>(ebuf, bcnt, cursor, csr);

    int nb16 = (per8 + 15) / 16;
    edge_out_kernel<<<nb16 * 8, 256, 0, stream>>>(qv, kb, cursor, csr, BoP, bo, out, N, per8);
}

// Round 16
// 278.379 us; speedup vs baseline: 1.0888x; 1.0259x over previous
//
#include <hip/hip_runtime.h>
#include <hip/hip_bf16.h>
#include <math.h>

// Graph transformer attention, round 16 (= R13 revert + int4 build loads):
//  - Two-phase build abandoned (R9/R14/R15 all lost to the 8x-reread filter:
//    the filter runs near L3 streaming BW and writes XCD-locally already).
//  - build_kernel: dst read as int4 (4 edges/lane/issue, 4x fewer load
//    instructions on the 410MB L3 stream); filter+atomic path unchanged.
//  - edge_out at floor (~125us across 3 structural rewrites; FETCH 390MB =
//    unique-line combinatorial minimum): full-head-per-lane, unchanged.
//  - Keep: qkv MFMA GEMM [Wq|Wv|Wk] perm + LDS-staged epilogue, dense
//    cursor, single-pass softmax, bf16 path, R8 fusion geometry.

#define CAP 64          // fixed slots per node (Poisson(16): P(deg>64)~2e-18)
#define BCHUNK 4096     // edges per chunk in build

typedef __attribute__((ext_vector_type(8))) short short8;
typedef __attribute__((ext_vector_type(4))) float f32x4;

__device__ inline unsigned short f2bf(float f) {
    unsigned u = __float_as_uint(f);
    unsigned r = u + 0x7fffu + ((u >> 16) & 1u);   // RNE
    return (unsigned short)(r >> 16);
}
__device__ inline float bfhi2f(unsigned u) { return __uint_as_float(u & 0xffff0000u); }
__device__ inline float bflo2f(unsigned u) { return __uint_as_float(u << 16); }

// Permuted fused weight column c' -> source:
//  c' in [0,128): Wq col c' ; [128,256): Wv col c'-128 ; [256,384): Wk col c'-256
__device__ inline float w_perm(const float* Wq, const float* Wk, const float* Wv,
                               int k, int c) {
    if (c < 128)  return Wq[k * 128 + c];
    if (c < 256)  return Wv[k * 128 + (c - 128)];
    return Wk[k * 128 + (c - 256)];
}

// ---------- pack B matrices into MFMA fragment layout (bf16) ----------
__global__ void pack_b_kernel(const float* __restrict__ Wq, const float* __restrict__ Wk,
                              const float* __restrict__ Wv, const float* __restrict__ Wo,
                              const float* __restrict__ bq, const float* __restrict__ bk,
                              const float* __restrict__ bv,
                              short* __restrict__ BqkvP, short* __restrict__ BoP,
                              float* __restrict__ bqkv) {
    int t = blockIdx.x * 256 + threadIdx.x;
    if (t < 24 * 4 * 64 * 8) {
        int j = t & 7, l = (t >> 3) & 63, ks = (t >> 9) & 3, ct = t >> 11;
        int c = ct * 16 + (l & 15);
        int k = ks * 32 + (l >> 4) * 8 + j;
        BqkvP[t] = (short)f2bf(w_perm(Wq, Wk, Wv, k, c));
    }
    if (t < 8 * 4 * 64 * 8) {
        int j = t & 7, l = (t >> 3) & 63, ks = (t >> 9) & 3, ct = t >> 11;
        int c = ct * 16 + (l & 15);
        int k = ks * 32 + (l >> 4) * 8 + j;
        BoP[t] = (short)f2bf(Wo[k * 128 + c]);
    }
    if (t < 384) {   // permuted bias [bq | bv | bk]
        float v;
        if (t < 128)      v = bq[t];
        else if (t < 256) v = bv[t - 128];
        else              v = bk[t - 256];
        bqkv[t] = v;
    }
}

// ---------- MFMA GEMM: [q|v|k] = x @ W' + b', LDS-staged bf16 epilogue ----------
#define QKV_STRIDE 392
__global__ __launch_bounds__(256) void gemm_qkv_mfma(const float* __restrict__ A,
        const short* __restrict__ Bp, const float* __restrict__ bias,
        short* __restrict__ qv, short* __restrict__ kb, int M) {
    __shared__ short stage[4][16][QKV_STRIDE];
    int w = threadIdx.x >> 6, l = threadIdx.x & 63;
    int row0 = blockIdx.x * 64 + w * 16;
    int lr = l & 15, lk = l >> 4;

    f32x4 acc[24];
    #pragma unroll
    for (int ct = 0; ct < 24; ++ct) {
        float b = bias[ct * 16 + lr];
        acc[ct][0] = b; acc[ct][1] = b; acc[ct][2] = b; acc[ct][3] = b;
    }

    int arow = row0 + lr;
    bool rowok = arow < M;
    const float* arp = A + (size_t)arow * 128;

    #pragma unroll
    for (int ks = 0; ks < 4; ++ks) {
        f32x4 a0 = {0.f, 0.f, 0.f, 0.f}, a1 = {0.f, 0.f, 0.f, 0.f};
        if (rowok) {
            a0 = *(const f32x4*)(arp + ks * 32 + lk * 8);
            a1 = *(const f32x4*)(arp + ks * 32 + lk * 8 + 4);
        }
        short8 af;
        af[0] = (short)f2bf(a0[0]); af[1] = (short)f2bf(a0[1]);
        af[2] = (short)f2bf(a0[2]); af[3] = (short)f2bf(a0[3]);
        af[4] = (short)f2bf(a1[0]); af[5] = (short)f2bf(a1[1]);
        af[6] = (short)f2bf(a1[2]); af[7] = (short)f2bf(a1[3]);
        #pragma unroll
        for (int ct = 0; ct < 24; ++ct) {
            short8 bf = *(const short8*)(Bp + ((size_t)(ct * 4 + ks) * 64 + l) * 8);
            acc[ct] = __builtin_amdgcn_mfma_f32_16x16x32_bf16(af, bf, acc[ct], 0, 0, 0);
        }
    }

    #pragma unroll
    for (int ct = 0; ct < 24; ++ct) {
        int c = ct * 16 + lr;
        #pragma unroll
        for (int j = 0; j < 4; ++j)
            stage[w][lk * 4 + j][c] = (short)f2bf(acc[ct][j]);
    }
    __syncthreads();

    #pragma unroll
    for (int it = 0; it < 8; ++it) {
        int rr = it * 2 + (l >> 5);
        int row = row0 + rr;
        if (row < M) {
            short8 vqv = *(const short8*)&stage[w][rr][(l & 31) * 8];
            *(short8*)(qv + (size_t)row * 256 + (l & 31) * 8) = vqv;
        }
    }
    #pragma unroll
    for (int it = 0; it < 4; ++it) {
        int rr = it * 4 + (l >> 4);
        int row = row0 + rr;
        if (row < M) {
            short8 vk = *(const short8*)&stage[w][rr][256 + (l & 15) * 8];
            *(short8*)(kb + (size_t)row * 128 + (l & 15) * 8) = vk;
        }
    }
}

// ---------- XCD-sharded fixed-capacity CSR build (int4 dst stream) ----------
__global__ __launch_bounds__(256) void build_kernel(const int* __restrict__ src,
        const int* __restrict__ dst, int* __restrict__ cursor, int* __restrict__ csr,
        int E, int per8) {
    int xcd = blockIdx.x & 7;
    int chunk = blockIdx.x >> 3;
    int lo = xcd * per8, hi = lo + per8;
    #pragma unroll
    for (int it = 0; it < BCHUNK / 1024; ++it) {
        int e0 = chunk * BCHUNK + it * 1024 + threadIdx.x * 4;
        if (e0 + 3 < E) {
            int4 d4 = *(const int4*)(dst + e0);
            #pragma unroll
            for (int j = 0; j < 4; ++j) {
                int d = (j == 0) ? d4.x : (j == 1) ? d4.y : (j == 2) ? d4.z : d4.w;
                if (d >= lo && d < hi) {
                    int s = src[e0 + j];   // only 1/8 of edges reach here
                    int slot = atomicAdd(&cursor[d], 1);
                    if (slot < CAP) csr[((size_t)d << 6) + slot] = s;
                }
            }
        } else {
            for (int j = 0; j < 4; ++j) {
                int e = e0 + j;
                if (e < E) {
                    int d = dst[e];
                    if (d >= lo && d < hi) {
                        int s = src[e];
                        int slot = atomicAdd(&cursor[d], 1);
                        if (slot < CAP) csr[((size_t)d << 6) + slot] = s;
                    }
                }
            }
        }
    }
}

// ---------- FUSED: edge attention + out-GEMM (full-head-per-lane, R13) ----------
#define AGG_STRIDE 68   // uints per staged row (64 data + 4 pad)

#define EDGE_ITER(EI, ACT)                                                     \
    {                                                                          \
        bool act = (ACT);                                                      \
        int s = act ? (EI) : 0;                                                \
        const uint4* qp = (const uint4*)(qv + (size_t)s * 256 + head * 16);    \
        uint4 qa = qp[0], qb = qp[1];                                          \
        uint4 va = qp[16], vb = qp[17];  /* v row-half: +128 shorts = +16 u4 */\
        float p = bflo2f(qa.x) * kf[0]  + bfhi2f(qa.x) * kf[1]                 \
                + bflo2f(qa.y) * kf[2]  + bfhi2f(qa.y) * kf[3]                 \
                + bflo2f(qa.z) * kf[4]  + bfhi2f(qa.z) * kf[5]                 \
                + bflo2f(qa.w) * kf[6]  + bfhi2f(qa.w) * kf[7]                 \
                + bflo2f(qb.x) * kf[8]  + bfhi2f(qb.x) * kf[9]                 \
                + bflo2f(qb.y) * kf[10] + bfhi2f(qb.y) * kf[11]                \
                + bflo2f(qb.z) * kf[12] + bfhi2f(qb.z) * kf[13]                \
                + bflo2f(qb.w) * kf[14] + bfhi2f(qb.w) * kf[15];               \
        float ee = act ? __expf(p * 0.25f) : 0.f;                              \
        z += ee;                                                               \
        ag[0]  += ee * bflo2f(va.x); ag[1]  += ee * bfhi2f(va.x);              \
        ag[2]  += ee * bflo2f(va.y); ag[3]  += ee * bfhi2f(va.y);              \
        ag[4]  += ee * bflo2f(va.z); ag[5]  += ee * bfhi2f(va.z);              \
        ag[6]  += ee * bflo2f(va.w); ag[7]  += ee * bfhi2f(va.w);              \
        ag[8]  += ee * bflo2f(vb.x); ag[9]  += ee * bfhi2f(vb.x);              \
        ag[10] += ee * bflo2f(vb.y); ag[11] += ee * bfhi2f(vb.y);              \
        ag[12] += ee * bflo2f(vb.z); ag[13] += ee * bfhi2f(vb.z);              \
        ag[14] += ee * bflo2f(vb.w); ag[15] += ee * bfhi2f(vb.w);              \
    }

__global__ __launch_bounds__(256) void edge_out_kernel(const short* __restrict__ qv,
        const short* __restrict__ kb, const int* __restrict__ cursor,
        const int* __restrict__ csr, const short* __restrict__ BoP,
        const float* __restrict__ bo, float* __restrict__ out, int N, int per8) {
    __shared__ unsigned aggLds[16][AGG_STRIDE];
    int w  = threadIdx.x >> 6;
    int l  = threadIdx.x & 63;
    int lr = l & 15, lk = l >> 4;
    int head = l & 7;       // full head (16 dims)
    int slot = l >> 3;      // edge slot 0..7
    int xcd = blockIdx.x & 7;
    int jb  = blockIdx.x >> 3;
    int sliceN = per8 < (N - xcd * per8) ? per8 : (N - xcd * per8);
    int local0 = jb * 16;

    #pragma unroll
    for (int q = 0; q < 4; ++q) {
        int i = w * 4 + q;
        int local = local0 + i;
        if (local < sliceN) {
            int d = xcd * per8 + local;
            int deg = cursor[d];
            int n = (deg < CAP) ? deg : CAP;
            const int* ep = csr + ((size_t)d << 6);

            const uint4* kp = (const uint4*)(kb + (size_t)d * 128 + head * 16);
            uint4 ka = kp[0], kc = kp[1];
            float kf[16];
            kf[0]  = bflo2f(ka.x); kf[1]  = bfhi2f(ka.x);
            kf[2]  = bflo2f(ka.y); kf[3]  = bfhi2f(ka.y);
            kf[4]  = bflo2f(ka.z); kf[5]  = bfhi2f(ka.z);
            kf[6]  = bflo2f(ka.w); kf[7]  = bfhi2f(ka.w);
            kf[8]  = bflo2f(kc.x); kf[9]  = bfhi2f(kc.x);
            kf[10] = bflo2f(kc.y); kf[11] = bfhi2f(kc.y);
            kf[12] = bflo2f(kc.z); kf[13] = bfhi2f(kc.z);
            kf[14] = bflo2f(kc.w); kf[15] = bfhi2f(kc.w);

            float z = 0.f;
            float ag[16];
            #pragma unroll
            for (int j = 0; j < 16; ++j) ag[j] = 0.f;

            for (int b0 = 0; b0 < n; b0 += 16) {
                int i0 = b0 + slot;          // <= 55: bin-safe
                int i1 = b0 + 8 + slot;      // <= 63: bin-safe
                int eA = ep[i0];
                int eB = ep[i1];
                EDGE_ITER(eA, i0 < n)
                EDGE_ITER(eB, i1 < n)
            }

            // slot-reduce (once per node): slots live in lane bits 3-5
            z += __shfl_xor(z, 8);
            z += __shfl_xor(z, 16);
            z += __shfl_xor(z, 32);
            #pragma unroll
            for (int j = 0; j < 16; ++j) {
                ag[j] += __shfl_xor(ag[j], 8);
                ag[j] += __shfl_xor(ag[j], 16);
                ag[j] += __shfl_xor(ag[j], 32);
            }

            float zi = (z > 0.f) ? 1.0f / z : 0.f;
            if (slot == 0) {   // lane 'head' writes dim-pairs [8*head, 8*head+8)
                #pragma unroll
                for (int j = 0; j < 8; ++j) {
                    unsigned pk = (unsigned)f2bf(ag[2 * j] * zi) |
                                  ((unsigned)f2bf(ag[2 * j + 1] * zi) << 16);
                    aggLds[i][head * 8 + j] = pk;
                }
            }
        }
    }
    __syncthreads();

    // cooperative 16-row out-GEMM; wave w -> col tiles 2w, 2w+1
    f32x4 acc[2];
    #pragma unroll
    for (int t = 0; t < 2; ++t) {
        float b = bo[(w * 2 + t) * 16 + lr];
        acc[t][0] = b; acc[t][1] = b; acc[t][2] = b; acc[t][3] = b;
    }

    #pragma unroll
    for (int ks = 0; ks < 4; ++ks) {
        short8 af = *(const short8*)&aggLds[lr][ks * 16 + lk * 4];
        #pragma unroll
        for (int t = 0; t < 2; ++t) {
            int ct = w * 2 + t;
            short8 bf = *(const short8*)(BoP + ((size_t)(ct * 4 + ks) * 64 + l) * 8);
            acc[t] = __builtin_amdgcn_mfma_f32_16x16x32_bf16(af, bf, acc[t], 0, 0, 0);
        }
    }

    #pragma unroll
    for (int t = 0; t < 2; ++t) {
        int c = (w * 2 + t) * 16 + lr;
        #pragma unroll
        for (int j = 0; j < 4; ++j) {
            int localr = local0 + lk * 4 + j;
            if (localr < sliceN) {
                int r = xcd * per8 + localr;
                out[(size_t)r * 128 + c] = acc[t][j];
            }
        }
    }
}

extern "C" void kernel_launch(void* const* d_in, const int* in_sizes, int n_in,
                              void* d_out, int out_size, void* d_ws, size_t ws_size,
                              hipStream_t stream) {
    const float* x   = (const float*)d_in[0];
    const int*   src = (const int*)d_in[1];
    const int*   dst = (const int*)d_in[2];
    const float* Wq  = (const float*)d_in[3];
    const float* bq  = (const float*)d_in[4];
    const float* Wk  = (const float*)d_in[5];
    const float* bk  = (const float*)d_in[6];
    const float* Wv  = (const float*)d_in[7];
    const float* bv  = (const float*)d_in[8];
    const float* Wo  = (const float*)d_in[9];
    const float* bo  = (const float*)d_in[10];
    float* out = (float*)d_out;

    int N = in_sizes[0] / 128;
    int E = in_sizes[1];
    int per8 = (N + 7) / 8;

    char* ws = (char*)d_ws;
    size_t off = 0;
    auto alloc = [&](size_t bytes) -> void* {
        void* p = ws + off;
        off = (off + bytes + 255) & ~(size_t)255;
        return p;
    };
    short* BqkvP  = (short*)alloc((size_t)24 * 4 * 64 * 8 * 2);
    short* BoP    = (short*)alloc((size_t)8 * 4 * 64 * 8 * 2);
    float* bqkv   = (float*)alloc(384 * 4);
    short* qv     = (short*)alloc((size_t)N * 256 * 2);    // [q128|v128] bf16
    short* kb     = (short*)alloc((size_t)N * 128 * 2);    // k bf16
    int* csr      = (int*)alloc((size_t)N * CAP * 4);      // fixed-capacity bins
    int* cursor   = (int*)alloc((size_t)N * 4);            // dense (slice-local lines)
    (void)ws_size; (void)n_in; (void)out_size;

    hipMemsetAsync(cursor, 0, (size_t)N * 4, stream);

    pack_b_kernel<<<192, 256, 0, stream>>>(Wq, Wk, Wv, Wo, bq, bk, bv, BqkvP, BoP, bqkv);

    gemm_qkv_mfma<<<(N + 63) / 64, 256, 0, stream>>>(x, BqkvP, bqkv, qv, kb, N);

    int nchunks = (E + BCHUNK - 1) / BCHUNK;
    build_kernel<<<nchunks * 8, 256, 0, stream>>>(src, dst, cursor, csr, E, per8);

    int nb16 = (per8 + 15) / 16;
    edge_out_kernel<<<nb16 * 8, 256, 0, stream>>>(qv, kb, cursor, csr, BoP, bo, out, N, per8);
}